// Round 14
// baseline (23.282 us; speedup 1.0000x reference)
//
#include <hip/hip_runtime.h>
#include <math.h>

// Problem constants (match reference)
#define BB 32
#define TT 50
#define HH 76
#define WW 76
#define NA 5
#define NC 20
#define KK 25           // 5 + NC
#define HW (HH*WW)      // 5776
#define NMAIN 91        // main blocks per batch (64 cells each, 2 waves split by targets)
#define GPB 92          // + 1 owner block per batch
#define NBLK (GPB*BB)   // 2944 partials
#define THALF 25        // targets per fp16x2 half (lo: t, hi: t+25)
#define USPLIT 13       // wave 0: u in [0,13), wave 1: u in [13,25)

typedef _Float16 h2 __attribute__((ext_vector_type(2)));

static __device__ __forceinline__ h2 i2h(int i) { return __builtin_bit_cast(h2, i); }
static __device__ __forceinline__ int h2toi(h2 v) { return __builtin_bit_cast(int, v); }
static __device__ __forceinline__ h2 f2h2(float x) {
    _Float16 h = (_Float16)x; h2 r; r.x = h; r.y = h; return r;
}
// pack own target's f16 bits (lo) with lane (lane+25)'s f16 bits (hi).
// Only lanes 0..24 are ever readlane'd, so garbage in lanes >=25 is harmless.
static __device__ __forceinline__ int pack2t(float x, int lane) {
    unsigned short b = __builtin_bit_cast(unsigned short, (_Float16)x);
    int lo = (int)b;
    int hi = __shfl(lo, lane + THALF, 64);
    return (lo & 0xFFFF) | (hi << 16);
}

// packed-fp16 pair test: one anchor (both halves) vs two targets (lo/hi).
// hit <=> max over all fma values > thr (f32 compare; fp16->f32 exact).
// ih unclamped is sign-exact: ih<0 => max(iw,0)*ih <= 0 and sna < 0 => no hit.
// The multiset of fma values is identical no matter how the u-range is split
// across waves (slot-independent pk ops, same fp16 inputs); max is
// order-invariant, so main (split loop) and owner (full loop) agree exactly
// and the owner's noobj subtraction cancels the main path's term exactly.
#define IOU_STEP_PK(AX1, AX2, AY1, AY2, ACC) do {                              \
    h2 iw_ = __builtin_elementwise_min((AX2), sx2)                             \
           - __builtin_elementwise_max((AX1), sx1);                            \
    h2 ih_ = __builtin_elementwise_min((AY2), sy2)                             \
           - __builtin_elementwise_max((AY1), sy1);                            \
    iw_ = __builtin_elementwise_max(iw_, zero2);                               \
    (ACC) = __builtin_elementwise_max((ACC),                                   \
            __builtin_elementwise_fma(iw_, ih_, sna)); } while (0)

#define RL5(U) \
    h2 sx1 = i2h(__builtin_amdgcn_readlane(vx1i, (U))); \
    h2 sx2 = i2h(__builtin_amdgcn_readlane(vx2i, (U))); \
    h2 sy1 = i2h(__builtin_amdgcn_readlane(vy1i, (U))); \
    h2 sy2 = i2h(__builtin_amdgcn_readlane(vy2i, (U))); \
    h2 sna = i2h(__builtin_amdgcn_readlane(vnai, (U)));

__global__ __launch_bounds__(128) void fused_kernel(
    const float* __restrict__ out, const float* __restrict__ tgt,
    const float* __restrict__ pri, float* __restrict__ partial)
{
    const int b  = blockIdx.y;
    const int gx = blockIdx.x;
    const int tid  = threadIdx.x;         // 0..127 (2 waves)
    const int wid  = tid >> 6;            // wave id 0/1
    const int lane = tid & 63;
    const int tl = (lane < TT) ? lane : (TT - 1);
    const h2 zero2 = f2h2(0.0f);

    __shared__ int   lacc[64][NA];        // wave1 -> wave0 acc exchange
    __shared__ float swave[2];

    // wave-held target table, built under FULL exec in BOTH waves (identical):
    // lane u (u<25) holds targets (u, u+25) packed into fp16x2 lo/hi halves
    const float* tp = tgt + ((size_t)b * TT + tl) * 5;
    float bx = tp[1], by = tp[2], bw = tp[3], bh = tp[4];
    const int vx1i = pack2t(fmaf(-0.5f, bw, bx), lane);
    const int vx2i = pack2t(fmaf( 0.5f, bw, bx), lane);
    const int vy1i = pack2t(fmaf(-0.5f, bh, by), lane);
    const int vy2i = pack2t(fmaf( 0.5f, bh, by), lane);
    const int vnai = pack2t(-0.375f * (bw * bh), lane);

    float mysum = 0.0f;

    if (gx < NMAIN) {
        // ---- main path: 64 cells/block, both waves setup identically,
        //      target loop split across waves, pk-max combined via LDS ----
        int k = gx * 64 + lane;
        float valid = (k < HW) ? 1.0f : 0.0f;
        int rem = (k < HW) ? k : (HW - 1);
        int h = rem / WW;
        int w = rem - h * WW;

        const float* op0 = out + (size_t)b * KK * NA * HW + rem;
        h2 ax1h[NA], ax2h[NA], ay1h[NA], ay2h[NA], acch[NA];
        _Float16 thr16[NA];
        float o4v[NA];
        #pragma unroll
        for (int n = 0; n < NA; ++n) {
            const float* op = op0 + (size_t)(n * KK) * HW;
            float o0 = op[0];
            float o1 = op[HW];
            float o2 = op[2*HW];
            float o3 = op[3*HW];
            o4v[n] = op[4*HW];
            float px = ((float)w + o0) * (1.0f/WW);
            float py = ((float)h + o1) * (1.0f/HH);
            float pw = pri[2*n]   * __expf(o2) * (1.0f/WW);
            float ph = pri[2*n+1] * __expf(o3) * (1.0f/HH);
            ax1h[n] = f2h2(fmaf(-0.5f, pw, px));
            ax2h[n] = f2h2(fmaf( 0.5f, pw, px));
            ay1h[n] = f2h2(fmaf(-0.5f, ph, py));
            ay2h[n] = f2h2(fmaf( 0.5f, ph, py));
            thr16[n] = (_Float16)(0.375f * (pw * ph));
            acch[n] = zero2;
        }

        if (wid == 0) {
            #pragma unroll
            for (int u = 0; u < USPLIT; ++u) {
                RL5(u);
                IOU_STEP_PK(ax1h[0], ax2h[0], ay1h[0], ay2h[0], acch[0]);
                IOU_STEP_PK(ax1h[1], ax2h[1], ay1h[1], ay2h[1], acch[1]);
                IOU_STEP_PK(ax1h[2], ax2h[2], ay1h[2], ay2h[2], acch[2]);
                IOU_STEP_PK(ax1h[3], ax2h[3], ay1h[3], ay2h[3], acch[3]);
                IOU_STEP_PK(ax1h[4], ax2h[4], ay1h[4], ay2h[4], acch[4]);
            }
        } else {
            #pragma unroll
            for (int u = USPLIT; u < THALF; ++u) {
                RL5(u);
                IOU_STEP_PK(ax1h[0], ax2h[0], ay1h[0], ay2h[0], acch[0]);
                IOU_STEP_PK(ax1h[1], ax2h[1], ay1h[1], ay2h[1], acch[1]);
                IOU_STEP_PK(ax1h[2], ax2h[2], ay1h[2], ay2h[2], acch[2]);
                IOU_STEP_PK(ax1h[3], ax2h[3], ay1h[3], ay2h[3], acch[3]);
                IOU_STEP_PK(ax1h[4], ax2h[4], ay1h[4], ay2h[4], acch[4]);
            }
            #pragma unroll
            for (int n = 0; n < NA; ++n)
                lacc[lane][n] = h2toi(acch[n]);   // stride-5 words: conflict-free
        }
        __syncthreads();
        if (wid == 0) {
            float s = 0.0f;
            #pragma unroll
            for (int n = 0; n < NA; ++n) {
                h2 m2 = __builtin_elementwise_max(acch[n], i2h(lacc[lane][n]));
                float m = fmaxf((float)m2.x, (float)m2.y);
                s += (m > (float)thr16[n]) ? 0.0f : o4v[n] * o4v[n];
            }
            mysum = s * valid;
        }
    } else if (wid == 0) {
        // ---- owner wave (wave 0 of the per-batch owner block): FULLY UNIFORM
        // within the wave; liveness applied as a multiply. Lanes >= TT compute
        // masked duplicates of target TT-1. R13-verbatim. ----
        float cls = tp[0];
        int ci = (int)floorf(bx * WW);
        int cj = (int)floorf(by * HH);

        // anchor assignment: first-argmax IoU of (0,0,bw,bh) vs per-cell (pw,ph)
        const float* ob = out + (size_t)b * KK * NA * HW + (size_t)cj * WW + ci;
        float best = -1.0f; int bn = 0;
        #pragma unroll
        for (int n = 0; n < NA; ++n) {
            float e2 = ob[(size_t)(n*KK + 2) * HW];
            float e3 = ob[(size_t)(n*KK + 3) * HW];
            float pw = pri[2*n]   * __expf(e2) * (1.0f/WW);
            float ph = pri[2*n+1] * __expf(e3) * (1.0f/HH);
            float inter = fminf(bw, pw) * fminf(bh, ph);
            float iou = inter / (bw*bh + pw*ph - inter);
            if (iou > best) { best = iou; bn = n; }
        }
        int mycell = (cj*WW + ci)*NA + bn;   // produced under full wave exec

        // duplicate-target resolution: later t wins for the same cell
        bool dead = false;
        #pragma unroll 10
        for (int t2 = 0; t2 < TT; ++t2) {
            int c2 = __builtin_amdgcn_readlane(mycell, t2);
            dead = dead || (c2 == mycell && t2 > lane);
        }
        float live = (lane < TT && !dead) ? 1.0f : 0.0f;

        int rem = cj*WW + ci;
        const float* op = out + ((size_t)(b*NA + bn) * KK) * HW + rem;
        float o0 = op[0];
        float o1 = op[HW];
        float o2 = op[2*HW];
        float o3 = op[3*HW];
        float o4 = op[4*HW];

        float tx = bx * WW - (float)ci;
        float ty = by * HH - (float)cj;
        float tw = __logf(bw * WW / pri[2*bn]);
        float th = __logf(bh * HH / pri[2*bn+1]);
        if (tw != tw) tw = 0.0f;  // NaN guard (matches reference)
        if (th != th) th = 0.0f;
        float sc = 2.0f - bw * bh;

        float d0 = sc * (tx - o0);
        float d1 = sc * (ty - o1);
        float d2 = sc * (tw - o2);
        float d3 = sc * (th - o3);
        float dob = 5.0f * (1.0f - o4);
        float s = d0*d0 + d1*d1 + d2*d2 + d3*d3 + dob*dob;
        int tc = (int)floorf(cls);
        #pragma unroll
        for (int c = 0; c < NC; ++c) {
            float oc = op[(size_t)(5 + c) * HW];
            float d = ((c == tc) ? 1.0f : 0.0f) - oc;
            s += d * d;
        }

        // recompute this cell's iou-hit with the slot-identical fp16 chain
        // (full u loop; same fma multiset as the split main loop), subtract
        // the noobj term the main path added for this cell
        float px = ((float)ci + o0) * (1.0f/WW);
        float py = ((float)cj + o1) * (1.0f/HH);
        float pw = pri[2*bn]   * __expf(o2) * (1.0f/WW);
        float ph = pri[2*bn+1] * __expf(o3) * (1.0f/HH);
        h2 Ax1 = f2h2(fmaf(-0.5f, pw, px));
        h2 Ax2 = f2h2(fmaf( 0.5f, pw, px));
        h2 Ay1 = f2h2(fmaf(-0.5f, ph, py));
        h2 Ay2 = f2h2(fmaf( 0.5f, ph, py));
        _Float16 Thr16 = (_Float16)(0.375f * (pw * ph));
        h2 acc = zero2;
        #pragma unroll 5
        for (int u = 0; u < THALF; ++u) {
            RL5(u);
            IOU_STEP_PK(Ax1, Ax2, Ay1, Ay2, acc);
        }
        float m = fmaxf((float)acc.x, (float)acc.y);
        s -= (m > (float)Thr16) ? 0.0f : o4 * o4;
        mysum = s * live;
    }

    // deterministic reduction: per-wave shuffle, then combine 2 waves via LDS
    #pragma unroll
    for (int off = 32; off > 0; off >>= 1)
        mysum += __shfl_down(mysum, off, 64);
    if (lane == 0) swave[wid] = mysum;
    __syncthreads();
    if (tid == 0)
        partial[b * GPB + gx] = swave[0] + swave[1];
}

__global__ __launch_bounds__(256) void reduce_kernel(
    const float* __restrict__ partial, int n, float* __restrict__ outp)
{
    int tid = threadIdx.x;
    float s = 0.0f;
    for (int i = tid; i < n; i += 256) s += partial[i];
    #pragma unroll
    for (int off = 32; off > 0; off >>= 1)
        s += __shfl_down(s, off, 64);
    __shared__ float swave[4];
    if ((tid & 63) == 0) swave[tid >> 6] = s;
    __syncthreads();
    if (tid == 0) {
        float total = swave[0] + swave[1] + swave[2] + swave[3];
        float r = sqrtf(total);
        outp[0] = r * r;   // mirror reference: sqrt(sum)^2
    }
}

extern "C" void kernel_launch(void* const* d_in, const int* in_sizes, int n_in,
                              void* d_out, int out_size, void* d_ws, size_t ws_size,
                              hipStream_t stream) {
    const float* output = (const float*)d_in[0];
    const float* target = (const float*)d_in[1];
    const float* priors = (const float*)d_in[2];
    float* partial = (float*)d_ws;   // NBLK floats, fully overwritten each call

    fused_kernel<<<dim3(GPB, BB), 128, 0, stream>>>(output, target, priors, partial);
    reduce_kernel<<<1, 256, 0, stream>>>(partial, NBLK, (float*)d_out);
}

// Round 15
// 22.364 us; speedup vs baseline: 1.0411x; 1.0411x over previous
//
#include <hip/hip_runtime.h>
#include <math.h>

// Problem constants (match reference)
#define BB 32
#define TT 50
#define HH 76
#define WW 76
#define NA 5
#define NC 20
#define KK 25           // 5 + NC
#define HW (HH*WW)      // 5776
#define NMAIN 91        // main blocks per batch (64 spatial cells each)
#define GPB 92          // + 1 owner block per batch
#define NBLK (GPB*BB)   // 2944 partials
#define THALF 25        // targets per fp16x2 half (lo: t, hi: t+25)

typedef _Float16 h2 __attribute__((ext_vector_type(2)));

static __device__ __forceinline__ h2 i2h(int i) { return __builtin_bit_cast(h2, i); }
static __device__ __forceinline__ h2 f2h2(float x) {
    _Float16 h = (_Float16)x; h2 r; r.x = h; r.y = h; return r;
}
// pack own target's f16 bits (lo) with lane (tid+25)'s f16 bits (hi).
// Only lanes 0..24 are ever readlane'd, so garbage in lanes >=25 is harmless.
static __device__ __forceinline__ int pack2t(float x, int tid) {
    unsigned short b = __builtin_bit_cast(unsigned short, (_Float16)x);
    int lo = (int)b;
    int hi = __shfl(lo, tid + THALF, 64);
    return (lo & 0xFFFF) | (hi << 16);
}

// packed-fp16 pair test: one anchor (both halves) vs two targets (lo/hi).
// hit <=> max(acc.lo, acc.hi) > thr (compared in f32; fp16->f32 exact).
// ih unclamped is sign-exact: ih<0 => max(iw,0)*ih <= 0 and sna < 0 => no hit.
// IDENTICAL intrinsic chain in main & owner (pk halves are slot-independent),
// so the owner's noobj subtraction cancels the main path's term exactly.
#define IOU_STEP_PK(AX1, AX2, AY1, AY2, ACC) do {                              \
    h2 iw_ = __builtin_elementwise_min((AX2), sx2)                             \
           - __builtin_elementwise_max((AX1), sx1);                            \
    h2 ih_ = __builtin_elementwise_min((AY2), sy2)                             \
           - __builtin_elementwise_max((AY1), sy1);                            \
    iw_ = __builtin_elementwise_max(iw_, zero2);                               \
    (ACC) = __builtin_elementwise_max((ACC),                                   \
            __builtin_elementwise_fma(iw_, ih_, sna)); } while (0)

__global__ __launch_bounds__(64) void fused_kernel(
    const float* __restrict__ out, const float* __restrict__ tgt,
    const float* __restrict__ pri, float* __restrict__ partial)
{
    const int b  = blockIdx.y;
    const int gx = blockIdx.x;
    const int tid = threadIdx.x;          // 0..63, one wave per block
    const int tl = (tid < TT) ? tid : (TT - 1);
    const h2 zero2 = f2h2(0.0f);

    // wave-held target table, built under FULL exec (uniform control flow):
    // lane u (u<25) holds targets (u, u+25) packed into fp16x2 lo/hi halves
    const float* tp = tgt + ((size_t)b * TT + tl) * 5;
    float bx = tp[1], by = tp[2], bw = tp[3], bh = tp[4];
    const int vx1i = pack2t(fmaf(-0.5f, bw, bx), tid);
    const int vx2i = pack2t(fmaf( 0.5f, bw, bx), tid);
    const int vy1i = pack2t(fmaf(-0.5f, bh, by), tid);
    const int vy2i = pack2t(fmaf( 0.5f, bh, by), tid);
    const int vnai = pack2t(-0.375f * (bw * bh), tid);

    float mysum = 0.0f;

    if (gx < NMAIN) {
        // ---- main path: one spatial pos per lane, all 5 anchors ----
        int k = gx * 64 + tid;
        float valid = (k < HW) ? 1.0f : 0.0f;
        int rem = (k < HW) ? k : (HW - 1);
        int h = rem / WW;
        int w = rem - h * WW;

        const float* op0 = out + (size_t)b * KK * NA * HW + rem;
        h2 ax1h[NA], ax2h[NA], ay1h[NA], ay2h[NA], acch[NA];
        _Float16 thr16[NA];
        float o4v[NA];
        #pragma unroll
        for (int n = 0; n < NA; ++n) {
            const float* op = op0 + (size_t)(n * KK) * HW;
            float o0 = op[0];
            float o1 = op[HW];
            float o2 = op[2*HW];
            float o3 = op[3*HW];
            o4v[n] = op[4*HW];
            float px = ((float)w + o0) * (1.0f/WW);
            float py = ((float)h + o1) * (1.0f/HH);
            float pw = pri[2*n]   * __expf(o2) * (1.0f/WW);
            float ph = pri[2*n+1] * __expf(o3) * (1.0f/HH);
            ax1h[n] = f2h2(fmaf(-0.5f, pw, px));
            ax2h[n] = f2h2(fmaf( 0.5f, pw, px));
            ay1h[n] = f2h2(fmaf(-0.5f, ph, py));
            ay2h[n] = f2h2(fmaf( 0.5f, ph, py));
            thr16[n] = (_Float16)(0.375f * (pw * ph));
            acch[n] = zero2;
        }

        #pragma unroll 5
        for (int u = 0; u < THALF; ++u) {
            h2 sx1 = i2h(__builtin_amdgcn_readlane(vx1i, u));
            h2 sx2 = i2h(__builtin_amdgcn_readlane(vx2i, u));
            h2 sy1 = i2h(__builtin_amdgcn_readlane(vy1i, u));
            h2 sy2 = i2h(__builtin_amdgcn_readlane(vy2i, u));
            h2 sna = i2h(__builtin_amdgcn_readlane(vnai, u));
            IOU_STEP_PK(ax1h[0], ax2h[0], ay1h[0], ay2h[0], acch[0]);
            IOU_STEP_PK(ax1h[1], ax2h[1], ay1h[1], ay2h[1], acch[1]);
            IOU_STEP_PK(ax1h[2], ax2h[2], ay1h[2], ay2h[2], acch[2]);
            IOU_STEP_PK(ax1h[3], ax2h[3], ay1h[3], ay2h[3], acch[3]);
            IOU_STEP_PK(ax1h[4], ax2h[4], ay1h[4], ay2h[4], acch[4]);
        }

        // per-anchor hit test: combine halves in f32 (exact), compare vs f16 thr
        float s = 0.0f;
        #pragma unroll
        for (int n = 0; n < NA; ++n) {
            float m = fmaxf((float)acch[n].x, (float)acch[n].y);
            s += (m > (float)thr16[n]) ? 0.0f : o4v[n] * o4v[n];
        }
        mysum = s * valid;
    } else {
        // ---- owner wave: FULLY UNIFORM; liveness applied as a multiply.
        // Lanes >= TT compute masked duplicates of target TT-1. ----
        float cls = tp[0];
        int ci = (int)floorf(bx * WW);
        int cj = (int)floorf(by * HH);

        // anchor assignment: first-argmax IoU of (0,0,bw,bh) vs per-cell (pw,ph)
        const float* ob = out + (size_t)b * KK * NA * HW + (size_t)cj * WW + ci;
        float best = -1.0f; int bn = 0;
        #pragma unroll
        for (int n = 0; n < NA; ++n) {
            float e2 = ob[(size_t)(n*KK + 2) * HW];
            float e3 = ob[(size_t)(n*KK + 3) * HW];
            float pw = pri[2*n]   * __expf(e2) * (1.0f/WW);
            float ph = pri[2*n+1] * __expf(e3) * (1.0f/HH);
            float inter = fminf(bw, pw) * fminf(bh, ph);
            float iou = inter / (bw*bh + pw*ph - inter);
            if (iou > best) { best = iou; bn = n; }
        }
        int mycell = (cj*WW + ci)*NA + bn;   // produced under full exec

        // duplicate-target resolution: later t wins for the same cell
        bool dead = false;
        #pragma unroll 10
        for (int t2 = 0; t2 < TT; ++t2) {
            int c2 = __builtin_amdgcn_readlane(mycell, t2);
            dead = dead || (c2 == mycell && t2 > tid);
        }
        float live = (tid < TT && !dead) ? 1.0f : 0.0f;

        int rem = cj*WW + ci;
        const float* op = out + ((size_t)(b*NA + bn) * KK) * HW + rem;
        float o0 = op[0];
        float o1 = op[HW];
        float o2 = op[2*HW];
        float o3 = op[3*HW];
        float o4 = op[4*HW];

        float tx = bx * WW - (float)ci;
        float ty = by * HH - (float)cj;
        float tw = __logf(bw * WW / pri[2*bn]);
        float th = __logf(bh * HH / pri[2*bn+1]);
        if (tw != tw) tw = 0.0f;  // NaN guard (matches reference)
        if (th != th) th = 0.0f;
        float sc = 2.0f - bw * bh;

        float d0 = sc * (tx - o0);
        float d1 = sc * (ty - o1);
        float d2 = sc * (tw - o2);
        float d3 = sc * (th - o3);
        float dob = 5.0f * (1.0f - o4);
        float s = d0*d0 + d1*d1 + d2*d2 + d3*d3 + dob*dob;
        int tc = (int)floorf(cls);
        #pragma unroll
        for (int c = 0; c < NC; ++c) {
            float oc = op[(size_t)(5 + c) * HW];
            float d = ((c == tc) ? 1.0f : 0.0f) - oc;
            s += d * d;
        }

        // recompute this cell's iou-hit with the slot-identical fp16 chain
        // (anchor bn in both halves, targets split lo/hi), subtract the
        // noobj term the main path added for this cell
        float px = ((float)ci + o0) * (1.0f/WW);
        float py = ((float)cj + o1) * (1.0f/HH);
        float pw = pri[2*bn]   * __expf(o2) * (1.0f/WW);
        float ph = pri[2*bn+1] * __expf(o3) * (1.0f/HH);
        h2 Ax1 = f2h2(fmaf(-0.5f, pw, px));
        h2 Ax2 = f2h2(fmaf( 0.5f, pw, px));
        h2 Ay1 = f2h2(fmaf(-0.5f, ph, py));
        h2 Ay2 = f2h2(fmaf( 0.5f, ph, py));
        _Float16 Thr16 = (_Float16)(0.375f * (pw * ph));
        h2 acc = zero2;
        #pragma unroll 5
        for (int u = 0; u < THALF; ++u) {
            h2 sx1 = i2h(__builtin_amdgcn_readlane(vx1i, u));
            h2 sx2 = i2h(__builtin_amdgcn_readlane(vx2i, u));
            h2 sy1 = i2h(__builtin_amdgcn_readlane(vy1i, u));
            h2 sy2 = i2h(__builtin_amdgcn_readlane(vy2i, u));
            h2 sna = i2h(__builtin_amdgcn_readlane(vnai, u));
            IOU_STEP_PK(Ax1, Ax2, Ay1, Ay2, acc);
        }
        float m = fmaxf((float)acc.x, (float)acc.y);
        s -= (m > (float)Thr16) ? 0.0f : o4 * o4;
        mysum = s * live;
    }

    // deterministic single-wave reduction, one store per block (no LDS, no sync)
    #pragma unroll
    for (int off = 32; off > 0; off >>= 1)
        mysum += __shfl_down(mysum, off, 64);
    if (tid == 0)
        partial[b * GPB + gx] = mysum;
}

__global__ __launch_bounds__(256) void reduce_kernel(
    const float* __restrict__ partial, int n, float* __restrict__ outp)
{
    int tid = threadIdx.x;
    float s = 0.0f;
    for (int i = tid; i < n; i += 256) s += partial[i];
    #pragma unroll
    for (int off = 32; off > 0; off >>= 1)
        s += __shfl_down(s, off, 64);
    __shared__ float swave[4];
    if ((tid & 63) == 0) swave[tid >> 6] = s;
    __syncthreads();
    if (tid == 0) {
        float total = swave[0] + swave[1] + swave[2] + swave[3];
        float r = sqrtf(total);
        outp[0] = r * r;   // mirror reference: sqrt(sum)^2
    }
}

extern "C" void kernel_launch(void* const* d_in, const int* in_sizes, int n_in,
                              void* d_out, int out_size, void* d_ws, size_t ws_size,
                              hipStream_t stream) {
    const float* output = (const float*)d_in[0];
    const float* target = (const float*)d_in[1];
    const float* priors = (const float*)d_in[2];
    float* partial = (float*)d_ws;   // NBLK floats, fully overwritten each call

    fused_kernel<<<dim3(GPB, BB), 64, 0, stream>>>(output, target, priors, partial);
    reduce_kernel<<<1, 256, 0, stream>>>(partial, NBLK, (float*)d_out);
}